// Round 3
// baseline (1820.924 us; speedup 1.0000x reference)
//
#include <hip/hip_runtime.h>
#include <math.h>
#include <float.h>

#define N_USERS 65536
#define N_ENT   8192
#define CDIM    64
#define N_RELM1 15
#define E_EDGES 1000000
#define NNZV    1000000
#define TOPK    10
#define NCAND   12
#define EPSN    1e-12f

typedef float f32x4 __attribute__((ext_vector_type(4)));
typedef short short8 __attribute__((ext_vector_type(8)));

// ---------------- wave helpers (wave64) ----------------
__device__ inline float wred_sum(float v){
#pragma unroll
  for (int m = 32; m; m >>= 1) v += __shfl_xor(v, m, 64);
  return v;
}
__device__ inline float wred_max(float v){
#pragma unroll
  for (int m = 32; m; m >>= 1) v = fmaxf(v, __shfl_xor(v, m, 64));
  return v;
}

// bf16 RNE from f32 bits
__device__ inline unsigned bf16_rne(float x){
  unsigned u = __float_as_uint(x);
  return (u + 0x7FFFu + ((u >> 16) & 1u)) >> 16;
}

// ---------------- row L2-normalize + f32 copy + bf16 hi/lo split ----------------
__global__ void k_rownorm_split(const float* __restrict__ x, float* __restrict__ cn,
                                short* __restrict__ hi, short* __restrict__ lo, int n){
  int w = (blockIdx.x * blockDim.x + threadIdx.x) >> 6;
  int lane = threadIdx.x & 63;
  if (w >= n) return;
  float v = x[w * CDIM + lane];
  float ss = wred_sum(v * v);
  float c = v / sqrtf(ss);
  cn[w * CDIM + lane] = c;
  unsigned h = bf16_rne(c);
  float hf = __uint_as_float(h << 16);
  unsigned l2 = bf16_rne(c - hf);
  hi[w * CDIM + lane] = (short)h;
  lo[w * CDIM + lane] = (short)l2;
}

// ---------------- MFMA split-bf16 screening: per-row top-12 candidate indices ----------------
// block: 32 rows, 4 waves; wave w: rowset (w>>1)*16, col-half (w&1)*4096
__global__ __launch_bounds__(256) void k_sim_topk(const short* __restrict__ hi,
                                                  const short* __restrict__ lo,
                                                  int* __restrict__ cand){
  __shared__ float cval[16 * 384];
  __shared__ int   cidx[16 * 384];
  const int tid = threadIdx.x;
  const int w = tid >> 6, l = tid & 63;
  const int c = l & 15, q = l >> 4;
  const int rowset = (w >> 1) << 4;
  const int half = w & 1;
  const int row0 = blockIdx.x * 32 + rowset;

  // A fragments: lane holds A[row=c][k=8q..8q+7]; K=64 -> 2 frags
  const short8 a_hi0 = *(const short8*)(hi + (size_t)(row0 + c) * CDIM + 8 * q);
  const short8 a_hi1 = *(const short8*)(hi + (size_t)(row0 + c) * CDIM + 32 + 8 * q);
  const short8 a_lo0 = *(const short8*)(lo + (size_t)(row0 + c) * CDIM + 8 * q);
  const short8 a_lo1 = *(const short8*)(lo + (size_t)(row0 + c) * CDIM + 32 + 8 * q);

  float tv[4][NCAND]; int ti[4][NCAND];
#pragma unroll
  for (int s = 0; s < 4; ++s)
#pragma unroll
    for (int t = 0; t < NCAND; ++t){ tv[s][t] = -FLT_MAX; ti[s][t] = 0x7FFFFFFF; }

  const int ct0 = half * 256;
  const f32x4 z4 = {0.f, 0.f, 0.f, 0.f};
  for (int ct = ct0; ct < ct0 + 256; ++ct){
    const size_t boff = (size_t)(ct * 16 + c) * CDIM + 8 * q;
    short8 b_hi0 = *(const short8*)(hi + boff);
    short8 b_hi1 = *(const short8*)(hi + boff + 32);
    short8 b_lo0 = *(const short8*)(lo + boff);
    short8 b_lo1 = *(const short8*)(lo + boff + 32);
    f32x4 p0 = __builtin_amdgcn_mfma_f32_16x16x32_bf16(a_hi0, b_hi0, z4, 0, 0, 0);
    f32x4 p1 = __builtin_amdgcn_mfma_f32_16x16x32_bf16(a_hi0, b_lo0, z4, 0, 0, 0);
    f32x4 p2 = __builtin_amdgcn_mfma_f32_16x16x32_bf16(a_lo0, b_hi0, z4, 0, 0, 0);
    p0 = __builtin_amdgcn_mfma_f32_16x16x32_bf16(a_hi1, b_hi1, p0, 0, 0, 0);
    p1 = __builtin_amdgcn_mfma_f32_16x16x32_bf16(a_hi1, b_lo1, p1, 0, 0, 0);
    p2 = __builtin_amdgcn_mfma_f32_16x16x32_bf16(a_lo1, b_hi1, p2, 0, 0, 0);
    const int j = ct * 16 + c;
#pragma unroll
    for (int s = 0; s < 4; ++s){
      float v = p0[s] + p1[s] + p2[s];
      if (v > tv[s][NCAND - 1]){
        tv[s][NCAND - 1] = v; ti[s][NCAND - 1] = j;
#pragma unroll
        for (int p = NCAND - 1; p > 0; --p){
          if (tv[s][p] > tv[s][p - 1]){
            float tf = tv[s][p]; tv[s][p] = tv[s][p - 1]; tv[s][p - 1] = tf;
            int tii = ti[s][p]; ti[s][p] = ti[s][p - 1]; ti[s][p - 1] = tii;
          }
        }
      }
    }
  }

  // two-pass merge (rows 0..15 then 16..31), 48 KB LDS
  for (int pass = 0; pass < 2; ++pass){
    __syncthreads();
    if ((w >> 1) == pass){
#pragma unroll
      for (int s = 0; s < 4; ++s)
#pragma unroll
        for (int t = 0; t < NCAND; ++t){
          int rr = 4 * q + s;
          cval[rr * 384 + (half * 16 + c) * NCAND + t] = tv[s][t];
          cidx[rr * 384 + (half * 16 + c) * NCAND + t] = ti[s][t];
        }
    }
    __syncthreads();
    for (int rr = w; rr < 16; rr += 4){
      float cv[6]; int ci[6];
#pragma unroll
      for (int t = 0; t < 6; ++t){
        cv[t] = cval[rr * 384 + l + 64 * t];
        ci[t] = cidx[rr * 384 + l + 64 * t];
      }
      const int grow = blockIdx.x * 32 + pass * 16 + rr;
      for (int k = 0; k < NCAND; ++k){
        float bv = cv[0]; int bi = ci[0];
#pragma unroll
        for (int t = 1; t < 6; ++t)
          if (cv[t] > bv || (cv[t] == bv && ci[t] < bi)){ bv = cv[t]; bi = ci[t]; }
#pragma unroll
        for (int m = 32; m; m >>= 1){
          float ov = __shfl_xor(bv, m, 64); int oi = __shfl_xor(bi, m, 64);
          if (ov > bv || (ov == bv && oi < bi)){ bv = ov; bi = oi; }
        }
#pragma unroll
        for (int t = 0; t < 6; ++t) if (ci[t] == bi) cv[t] = -FLT_MAX;
        if (l == 0) cand[(size_t)grow * NCAND + k] = bi;
      }
    }
  }
}

// ---------------- exact f32 refinement: top-10 of the 12 candidates + D^-1/2 ----------------
__global__ __launch_bounds__(256) void k_refine(const float* __restrict__ cn,
                                                const int* __restrict__ cand,
                                                float* __restrict__ kv, int* __restrict__ ki,
                                                float* __restrict__ dvec){
  int row = blockIdx.x * 4 + (threadIdx.x >> 6);
  int lane = threadIdx.x & 63;
  float v = cn[(size_t)row * CDIM + lane];
  float dv[NCAND]; int ji[NCAND];
#pragma unroll
  for (int t = 0; t < NCAND; ++t){
    ji[t] = cand[(size_t)row * NCAND + t];
    dv[t] = wred_sum(v * cn[(size_t)ji[t] * CDIM + lane]);
  }
  unsigned used = 0;
  float rs = 0.f;
  for (int k = 0; k < TOPK; ++k){
    float bv = -FLT_MAX; int bi = 0x7FFFFFFF; int bs = 0;
#pragma unroll
    for (int t = 0; t < NCAND; ++t){
      if (used & (1u << t)) continue;
      if (dv[t] > bv || (dv[t] == bv && ji[t] < bi)){ bv = dv[t]; bi = ji[t]; bs = t; }
    }
    used |= 1u << bs; rs += bv;
    if (lane == 0){ kv[(size_t)row * TOPK + k] = bv; ki[(size_t)row * TOPK + k] = bi; }
  }
  if (lane == 0) dvec[row] = 1.0f / sqrtf(rs);
}

// ---------------- CSR build ----------------
__global__ void k_hist(const int* __restrict__ keys, int* __restrict__ deg, int n){
  int e = blockIdx.x * blockDim.x + threadIdx.x;
  if (e < n) atomicAdd(&deg[keys[e]], 1);
}
__global__ __launch_bounds__(1024) void k_scan_local(const int* __restrict__ deg,
                                                     int* __restrict__ out,
                                                     int* __restrict__ part){
  __shared__ int sh[1024];
  int tid = threadIdx.x, g = blockIdx.x * 1024 + tid;
  int v = deg[g];
  sh[tid] = v; __syncthreads();
  for (int off = 1; off < 1024; off <<= 1){
    int t = (tid >= off) ? sh[tid - off] : 0;
    __syncthreads();
    sh[tid] += t;
    __syncthreads();
  }
  out[g] = sh[tid] - v;
  if (tid == 1023) part[blockIdx.x] = sh[1023];
}
__global__ void k_scan_part(int* __restrict__ part, int* __restrict__ total_out, int nb){
  int tid = threadIdx.x;                 // 1 wave
  int v = (tid < nb) ? part[tid] : 0;
  int orig = v;
  for (int off = 1; off < 64; off <<= 1){
    int t = __shfl_up(v, off, 64);
    if (tid >= off) v += t;
  }
  if (tid < nb) part[tid] = v - orig;
  if (tid == 63) *total_out = v;
}
__global__ __launch_bounds__(1024) void k_scan_add(int* __restrict__ out, const int* __restrict__ part){
  int g = blockIdx.x * 1024 + threadIdx.x;
  out[g] += part[blockIdx.x];
}
__global__ void k_scatter_graph(const int* __restrict__ head, const int* __restrict__ tail,
                                const int* __restrict__ etype, const int* __restrict__ rowptr,
                                int* __restrict__ cnt, int* __restrict__ pack, int n){
  int e = blockIdx.x * blockDim.x + threadIdx.x;
  if (e >= n) return;
  int h = head[e];
  int pos = rowptr[h] + atomicAdd(&cnt[h], 1);
  pack[pos] = tail[e] | ((etype[e] - 1) << 16);
}
__global__ void k_scatter_int(const int* __restrict__ rows, const int* __restrict__ cols,
                              const float* __restrict__ vals, const int* __restrict__ rowptr,
                              int* __restrict__ cnt, int* __restrict__ ocol,
                              float* __restrict__ oval, int n){
  int e = blockIdx.x * blockDim.x + threadIdx.x;
  if (e >= n) return;
  int r = rows[e];
  int pos = rowptr[r] + atomicAdd(&cnt[r], 1);
  ocol[pos] = cols[e];
  oval[pos] = vals[e];
}

// ---------------- nsq[e][r] = ||ent_e * w_r||^2 ----------------
__global__ __launch_bounds__(256) void k_normsq(const float* __restrict__ ent,
                                                const float* __restrict__ wmat,
                                                float* __restrict__ nsq){
  __shared__ float wl[N_RELM1 * CDIM];
  int tid = threadIdx.x;
  for (int t = tid; t < N_RELM1 * CDIM; t += 256) wl[t] = wmat[t];
  __syncthreads();
  int i = blockIdx.x * 4 + (tid >> 6);
  int lane = tid & 63;
  float v = ent[(size_t)i * CDIM + lane];
  float out = 0.f;
  for (int r = 0; r < N_RELM1; ++r){
    float t = v * wl[r * CDIM + lane];
    float ss = wred_sum(t * t);
    if (lane == r) out = ss;
  }
  if (lane < N_RELM1) nsq[i * N_RELM1 + lane] = out;
}

// ---------------- entity hop ----------------
__global__ __launch_bounds__(256) void k_entity_hop(const float* __restrict__ ent_cur,
                                                    const float* __restrict__ nsq,
                                                    const float* __restrict__ wmat,
                                                    const int* __restrict__ rowptr,
                                                    const int* __restrict__ pack,
                                                    float* __restrict__ ent_next,
                                                    float* __restrict__ res, int hop0){
  __shared__ float wl[N_RELM1 * CDIM];
  int tid = threadIdx.x;
  for (int t = tid; t < N_RELM1 * CDIM; t += 256) wl[t] = wmat[t];
  __syncthreads();
  int i = blockIdx.x * 4 + (tid >> 6);
  int lane = tid & 63;
  int beg = rowptr[i], end = rowptr[i + 1];

  float sm = 0.f;                                   // s >= 0 always
  for (int p = beg + lane; p < end; p += 64){
    int pk = pack[p]; int t = pk & 0xFFFF; int r = pk >> 16;
    sm = fmaxf(sm, nsq[i * N_RELM1 + r] * nsq[t * N_RELM1 + r]);
  }
  sm = wred_max(sm);

  float acc = 0.f, denom = 0.f;
  for (int p = beg; p < end; ++p){
    int pk = pack[p]; int t = pk & 0xFFFF; int r = pk >> 16;
    float s = nsq[i * N_RELM1 + r] * nsq[t * N_RELM1 + r];
    float e = expf(s - sm);
    denom += e;
    acc = fmaf(e * wl[r * CDIM + lane], ent_cur[(size_t)t * CDIM + lane], acc);
  }
  float agg = (end > beg) ? acc / denom : 0.f;
  float nrm = sqrtf(wred_sum(agg * agg));
  float out = agg / fmaxf(nrm, EPSN);
  if (hop0){
    ent_next[(size_t)i * CDIM + lane] = out;
    res[(size_t)i * CDIM + lane] = ent_cur[(size_t)i * CDIM + lane] + out;
  } else {
    res[(size_t)i * CDIM + lane] += out;
  }
}

// ---------------- user hop (hop2 reconstructs u-hat1 = res - base) ----------------
__global__ __launch_bounds__(256) void k_user_hop(const float* __restrict__ base,
                                                  const float* __restrict__ ent_cur,
                                                  const float* __restrict__ wmat,
                                                  const int* __restrict__ rowptr,
                                                  const int* __restrict__ cols,
                                                  const float* __restrict__ vals,
                                                  float* __restrict__ res, int hop0){
  __shared__ float wl[N_RELM1 * CDIM];
  int tid = threadIdx.x;
  for (int t = tid; t < N_RELM1 * CDIM; t += 256) wl[t] = wmat[t];
  __syncthreads();
  int u = blockIdx.x * 4 + (tid >> 6);
  int lane = tid & 63;
  float bv = base[(size_t)u * CDIM + lane];
  float rprev = hop0 ? bv : res[(size_t)u * CDIM + lane];
  float uv = hop0 ? bv : (rprev - bv);

  float dr[N_RELM1];
#pragma unroll
  for (int r = 0; r < N_RELM1; ++r) dr[r] = wred_sum(uv * wl[r * CDIM + lane]);
  float mx = dr[0];
#pragma unroll
  for (int r = 1; r < N_RELM1; ++r) mx = fmaxf(mx, dr[r]);
  float se = 0.f;
#pragma unroll
  for (int r = 0; r < N_RELM1; ++r){ dr[r] = expf(dr[r] - mx); se += dr[r]; }
  float m = 0.f;
#pragma unroll
  for (int r = 0; r < N_RELM1; ++r) m = fmaf(dr[r], wl[r * CDIM + lane], m);
  m /= se;

  int beg = rowptr[u], end = rowptr[u + 1];
  float acc = 0.f;
  for (int p = beg; p < end; ++p)
    acc = fmaf(vals[p], ent_cur[(size_t)cols[p] * CDIM + lane], acc);

  float u2 = acc * (1.f + m);
  float nrm = sqrtf(wred_sum(u2 * u2));
  float out = u2 / fmaxf(nrm, EPSN);
  res[(size_t)u * CDIM + lane] = rprev + out;
}

// ---------------- sparse scatter into dense adjacency ----------------
__global__ void k_scatter_adj(const float* __restrict__ kv, const int* __restrict__ ki,
                              const float* __restrict__ d, float* __restrict__ adj,
                              float coef, int use_atomic){
  int g = blockIdx.x * blockDim.x + threadIdx.x;
  if (g >= N_ENT * TOPK) return;
  int i = g / TOPK;
  int j = ki[g];
  float v = coef * d[i] * kv[g] * d[j];
  if (use_atomic) atomicAdd(&adj[(size_t)i * N_ENT + j], v);
  else            adj[(size_t)i * N_ENT + j] = v;
}

// ---------------- launch ----------------
extern "C" void kernel_launch(void* const* d_in, const int* in_sizes, int n_in,
                              void* d_out, int out_size, void* d_ws, size_t ws_size,
                              hipStream_t stream){
  const float* user_emb   = (const float*)d_in[0];
  const float* entity_emb = (const float*)d_in[1];
  const float* weight     = (const float*)d_in[2];
  const int*   head       = (const int*)d_in[3];
  const int*   tail       = head + E_EDGES;
  const int*   etype      = (const int*)d_in[4];
  const int*   irows      = (const int*)d_in[5];
  const int*   icols      = (const int*)d_in[6];
  const float* ivals      = (const float*)d_in[7];

  float* out_ent = (float*)d_out;
  float* out_usr = out_ent + (size_t)N_ENT * CDIM;
  float* out_adj = out_usr + (size_t)N_USERS * CDIM;

  // ---- workspace layout: padded, non-overlapping (fixes round-2 rowptr/cnt alias) ----
  char* W = (char*)d_ws;
  size_t off = 0;
  auto alloc = [&](size_t bytes) -> char* {
    char* p = W + off;
    off = (off + bytes + 1023) & ~(size_t)1023;
    return p;
  };
  float* cn       = (float*)alloc((size_t)N_ENT * CDIM * 4);       // 2 MB
  short* cn_hi    = (short*)alloc((size_t)N_ENT * CDIM * 2);       // 1 MB
  short* cn_lo    = (short*)alloc((size_t)N_ENT * CDIM * 2);       // 1 MB
  float* kv0      = (float*)alloc((size_t)N_ENT * TOPK * 4);
  int*   ki0      = (int*)  alloc((size_t)N_ENT * TOPK * 4);
  float* kv2      = (float*)alloc((size_t)N_ENT * TOPK * 4);
  int*   ki2      = (int*)  alloc((size_t)N_ENT * TOPK * 4);
  float* d0       = (float*)alloc((size_t)N_ENT * 4);
  float* d2       = (float*)alloc((size_t)N_ENT * 4);
  float* nsq      = (float*)alloc((size_t)N_ENT * N_RELM1 * 4);
  float* ent_a    = (float*)alloc((size_t)N_ENT * CDIM * 4);       // 2 MB
  int*   cand     = (int*)  alloc((size_t)N_ENT * NCAND * 4);
  int*   grp_rowptr = (int*)alloc((size_t)(N_ENT + 1) * 4);        // 8193 ints (padded)
  int*   grp_cnt    = (int*)alloc((size_t)N_ENT * 4);
  int*   grp_pack   = (int*)alloc((size_t)E_EDGES * 4);
  int*   int_rowptr = (int*)alloc((size_t)(N_USERS + 1) * 4);      // 65537 ints (padded)
  int*   int_cnt    = (int*)alloc((size_t)N_USERS * 4);
  int*   int_col    = (int*)alloc((size_t)NNZV * 4);
  float* int_val    = (float*)alloc((size_t)NNZV * 4);
  int*   scan_part  = (int*)alloc(256);

  const int EB = (E_EDGES + 255) / 256;

  // ---- graph CSR (by head) ----
  hipMemsetAsync(grp_cnt, 0, N_ENT * 4, stream);
  k_hist<<<EB, 256, 0, stream>>>(head, grp_cnt, E_EDGES);
  k_scan_local<<<N_ENT / 1024, 1024, 0, stream>>>(grp_cnt, grp_rowptr, scan_part);
  k_scan_part<<<1, 64, 0, stream>>>(scan_part, grp_rowptr + N_ENT, N_ENT / 1024);
  k_scan_add<<<N_ENT / 1024, 1024, 0, stream>>>(grp_rowptr, scan_part);
  hipMemsetAsync(grp_cnt, 0, N_ENT * 4, stream);
  k_scatter_graph<<<EB, 256, 0, stream>>>(head, tail, etype, grp_rowptr, grp_cnt, grp_pack, E_EDGES);

  // ---- interaction CSR (by user) ----
  hipMemsetAsync(int_cnt, 0, N_USERS * 4, stream);
  k_hist<<<EB, 256, 0, stream>>>(irows, int_cnt, NNZV);
  k_scan_local<<<N_USERS / 1024, 1024, 0, stream>>>(int_cnt, int_rowptr, scan_part);
  k_scan_part<<<1, 64, 0, stream>>>(scan_part, int_rowptr + N_USERS, N_USERS / 1024);
  k_scan_add<<<N_USERS / 1024, 1024, 0, stream>>>(int_rowptr, scan_part);
  hipMemsetAsync(int_cnt, 0, N_USERS * 4, stream);
  k_scatter_int<<<EB, 256, 0, stream>>>(irows, icols, ivals, int_rowptr, int_cnt, int_col, int_val, NNZV);

  // ---- origin adjacency (sparse form): screen -> refine ----
  k_rownorm_split<<<N_ENT / 4, 256, 0, stream>>>(entity_emb, cn, cn_hi, cn_lo, N_ENT);
  k_sim_topk<<<N_ENT / 32, 256, 0, stream>>>(cn_hi, cn_lo, cand);
  k_refine<<<N_ENT / 4, 256, 0, stream>>>(cn, cand, kv0, ki0, d0);

  // ---- hop 1 ----
  k_normsq<<<N_ENT / 4, 256, 0, stream>>>(entity_emb, weight, nsq);
  k_entity_hop<<<N_ENT / 4, 256, 0, stream>>>(entity_emb, nsq, weight, grp_rowptr, grp_pack, ent_a, out_ent, 1);
  k_user_hop<<<N_USERS / 4, 256, 0, stream>>>(user_emb, entity_emb, weight, int_rowptr, int_col, int_val, out_usr, 1);

  // ---- hop 2 ----
  k_normsq<<<N_ENT / 4, 256, 0, stream>>>(ent_a, weight, nsq);
  k_entity_hop<<<N_ENT / 4, 256, 0, stream>>>(ent_a, nsq, weight, grp_rowptr, grp_pack, ent_a, out_ent, 0);
  k_user_hop<<<N_USERS / 4, 256, 0, stream>>>(user_emb, ent_a, weight, int_rowptr, int_col, int_val, out_usr, 0);

  // ---- final adjacency: screen -> refine ----
  k_rownorm_split<<<N_ENT / 4, 256, 0, stream>>>(out_ent, cn, cn_hi, cn_lo, N_ENT);
  k_sim_topk<<<N_ENT / 32, 256, 0, stream>>>(cn_hi, cn_lo, cand);
  k_refine<<<N_ENT / 4, 256, 0, stream>>>(cn, cand, kv2, ki2, d2);

  hipMemsetAsync(out_adj, 0, (size_t)N_ENT * N_ENT * 4, stream);
  k_scatter_adj<<<(N_ENT * TOPK + 255) / 256, 256, 0, stream>>>(kv0, ki0, d0, out_adj, 0.5f, 0);
  k_scatter_adj<<<(N_ENT * TOPK + 255) / 256, 256, 0, stream>>>(kv2, ki2, d2, out_adj, 0.5f, 1);
}

// Round 5
// 1124.613 us; speedup vs baseline: 1.6192x; 1.6192x over previous
//
#include <hip/hip_runtime.h>
#include <math.h>
#include <float.h>

#define N_USERS 65536
#define N_ENT   8192
#define CDIM    64
#define N_RELM1 15
#define E_EDGES 1000000
#define NNZV    1000000
#define TOPK    10
#define NCAND   12
#define EPSN    1e-12f

typedef float f32x4 __attribute__((ext_vector_type(4)));
typedef short short8 __attribute__((ext_vector_type(8)));

__device__ inline unsigned umaxu(unsigned a, unsigned b){ return a > b ? a : b; }
__device__ inline unsigned uminu(unsigned a, unsigned b){ return a < b ? a : b; }

// ---------------- wave helpers (wave64) ----------------
__device__ inline float wred_sum(float v){
#pragma unroll
  for (int m = 32; m; m >>= 1) v += __shfl_xor(v, m, 64);
  return v;
}
__device__ inline float wred_max(float v){
#pragma unroll
  for (int m = 32; m; m >>= 1) v = fmaxf(v, __shfl_xor(v, m, 64));
  return v;
}

// bf16 RNE from f32 bits
__device__ inline unsigned bf16_rne(float x){
  unsigned u = __float_as_uint(x);
  return (u + 0x7FFFu + ((u >> 16) & 1u)) >> 16;
}

// ---------------- row L2-normalize + f32 copy + PERMUTED bf16 hi/lo split ----------------
// Permuted layout = MFMA fragment-major: element (row, k) -> tile T=row>>4, c=row&15,
// f=k>>5, q=(k>>3)&3, j=k&7 stored at ((T*2+f)*64 + q*16 + c)*8 + j.
// A wave's fragment load is then lane-contiguous 16B -> one coalesced 1KB dwordx4.
__global__ void k_rownorm_split(const float* __restrict__ x, float* __restrict__ cn,
                                short* __restrict__ hi_p, short* __restrict__ lo_p, int n){
  int w = (blockIdx.x * blockDim.x + threadIdx.x) >> 6;
  int k = threadIdx.x & 63;
  if (w >= n) return;
  float v = x[w * CDIM + k];
  float ss = wred_sum(v * v);
  float cv = v / sqrtf(ss);
  cn[w * CDIM + k] = cv;
  unsigned h = bf16_rne(cv);
  float hf = __uint_as_float(h << 16);
  unsigned l2 = bf16_rne(cv - hf);
  int T = w >> 4, c = w & 15;
  int f = k >> 5, q = (k >> 3) & 3, j = k & 7;
  size_t a = ((size_t)(T * 2 + f) * 64 + q * 16 + c) * 8 + j;
  hi_p[a] = (short)h;
  lo_p[a] = (short)l2;
}

// ---------------- MFMA split-bf16 screening ----------------
// grid (N_ENT/32, 2). Block: 4 waves; wave w: rowset (w>>1)*16, col range
// [cy*4096 + (w&1)*2048, +2048) scanned as 128 16-col tiles.
// Each lane keeps a branch-free sorted top-8 of packed keys per s (4 rows/lane).
// key = monotone-flipped f32 bits, low byte replaced by tile idx (quant err <= 2^-16 rel).
__global__ __launch_bounds__(256) void k_sim_topk(const short* __restrict__ hi_p,
                                                  const short* __restrict__ lo_p,
                                                  unsigned* __restrict__ keys){
  const int tid = threadIdx.x;
  const int w = tid >> 6, l = tid & 63;
  const int c = l & 15, q = l >> 4;
  const int rowset = (w >> 1) << 4;
  const int half = w & 1;
  const int cy = blockIdx.y;
  const int row0 = blockIdx.x * 32 + rowset;
  const int R = row0 >> 4;

  const short8* H8 = (const short8*)hi_p;
  const short8* L8 = (const short8*)lo_p;

  const short8 a_hi0 = H8[(size_t)R * 128 + l];
  const short8 a_hi1 = H8[(size_t)R * 128 + 64 + l];
  const short8 a_lo0 = L8[(size_t)R * 128 + l];
  const short8 a_lo1 = L8[(size_t)R * 128 + 64 + l];

  unsigned key[4][8];
#pragma unroll
  for (int s = 0; s < 4; ++s)
#pragma unroll
    for (int t = 0; t < 8; ++t) key[s][t] = 0u;

  const f32x4 z4 = {0.f, 0.f, 0.f, 0.f};
  const int bt = cy * 256 + half * 128;
#pragma unroll 2
  for (int lt = 0; lt < 128; ++lt){
    const size_t bo = (size_t)(bt + lt) * 128 + l;
    short8 b_hi0 = H8[bo];
    short8 b_hi1 = H8[bo + 64];
    short8 b_lo0 = L8[bo];
    short8 b_lo1 = L8[bo + 64];
    f32x4 p0 = __builtin_amdgcn_mfma_f32_16x16x32_bf16(a_hi0, b_hi0, z4, 0, 0, 0);
    f32x4 p1 = __builtin_amdgcn_mfma_f32_16x16x32_bf16(a_hi0, b_lo0, z4, 0, 0, 0);
    f32x4 p2 = __builtin_amdgcn_mfma_f32_16x16x32_bf16(a_lo0, b_hi0, z4, 0, 0, 0);
    p0 = __builtin_amdgcn_mfma_f32_16x16x32_bf16(a_hi1, b_hi1, p0, 0, 0, 0);
    p1 = __builtin_amdgcn_mfma_f32_16x16x32_bf16(a_hi1, b_lo1, p1, 0, 0, 0);
    p2 = __builtin_amdgcn_mfma_f32_16x16x32_bf16(a_lo1, b_hi1, p2, 0, 0, 0);
#pragma unroll
    for (int s = 0; s < 4; ++s){
      float v = p0[s] + p1[s] + p2[s];
      unsigned u = __float_as_uint(v);
      unsigned kk = ((u ^ (unsigned)(((int)u >> 31) | 0x80000000)) & 0xFFFFFF00u) | (unsigned)lt;
      // branch-free sorted-desc insert (drop min): 2 ops/slot, no index regs
#pragma unroll
      for (int i = 7; i >= 1; --i)
        key[s][i] = umaxu(uminu(key[s][i - 1], kk), key[s][i]);
      key[s][0] = umaxu(key[s][0], kk);
    }
  }

#pragma unroll
  for (int s = 0; s < 4; ++s){
    int grow = row0 + 4 * q + s;
    unsigned* kp = keys + ((size_t)grow * 64 + (size_t)(cy * 32 + half * 16 + c)) * 8;
    ((uint4*)kp)[0] = (uint4){key[s][0], key[s][1], key[s][2], key[s][3]};
    ((uint4*)kp)[1] = (uint4){key[s][4], key[s][5], key[s][6], key[s][7]};
  }
}

// ---------------- merge 64x8 keys -> top-12 -> exact f32 top-10 + D^-1/2 ----------------
__global__ __launch_bounds__(256) void k_refine(const float* __restrict__ cn,
                                                const unsigned* __restrict__ keys,
                                                float* __restrict__ kv, int* __restrict__ ki,
                                                float* __restrict__ dvec){
  int row = blockIdx.x * 4 + (threadIdx.x >> 6);
  int l = threadIdx.x & 63;
  const unsigned* kp = keys + ((size_t)row * 64 + l) * 8;
  uint4 k0 = ((const uint4*)kp)[0], k1 = ((const uint4*)kp)[1];
  unsigned kk0 = k0.x, kk1 = k0.y, kk2 = k0.z, kk3 = k0.w;
  unsigned kk4 = k1.x, kk5 = k1.y, kk6 = k1.z, kk7 = k1.w;
  const int cbase = (l >> 5) * 4096 + ((l >> 4) & 1) * 2048 + (l & 15);

  int ji[NCAND];
#pragma unroll
  for (int t = 0; t < NCAND; ++t){
    unsigned bk = kk0;
    int myc = cbase + (int)(kk0 & 0xFFu) * 16;
    int bc = myc;
#pragma unroll
    for (int m = 32; m; m >>= 1){
      unsigned ok = (unsigned)__shfl_xor((int)bk, m, 64);
      int oc = __shfl_xor(bc, m, 64);
      if (ok > bk || (ok == bk && oc < bc)){ bk = ok; bc = oc; }
    }
    if (kk0 == bk && myc == bc){   // pop my head (sentinel 0 < any real key)
      kk0 = kk1; kk1 = kk2; kk2 = kk3; kk3 = kk4; kk4 = kk5; kk5 = kk6; kk6 = kk7; kk7 = 0u;
    }
    ji[t] = bc;
  }

  float v = cn[(size_t)row * CDIM + l];
  float dv[NCAND];
#pragma unroll
  for (int t = 0; t < NCAND; ++t)
    dv[t] = wred_sum(v * cn[(size_t)ji[t] * CDIM + l]);

  unsigned used = 0;
  float rs = 0.f;
  for (int k = 0; k < TOPK; ++k){
    float bv = -FLT_MAX; int bi = 0x7FFFFFFF; int bs = 0;
#pragma unroll
    for (int t = 0; t < NCAND; ++t){
      if (used & (1u << t)) continue;
      if (dv[t] > bv || (dv[t] == bv && ji[t] < bi)){ bv = dv[t]; bi = ji[t]; bs = t; }
    }
    used |= 1u << bs; rs += bv;
    if (l == 0){ kv[(size_t)row * TOPK + k] = bv; ki[(size_t)row * TOPK + k] = bi; }
  }
  if (l == 0) dvec[row] = 1.0f / sqrtf(rs);
}

// ---------------- CSR build ----------------
__global__ void k_hist(const int* __restrict__ keys, int* __restrict__ deg, int n){
  int e = blockIdx.x * blockDim.x + threadIdx.x;
  if (e < n) atomicAdd(&deg[keys[e]], 1);
}
__global__ __launch_bounds__(1024) void k_scan_local(const int* __restrict__ deg,
                                                     int* __restrict__ out,
                                                     int* __restrict__ part){
  __shared__ int sh[1024];
  int tid = threadIdx.x, g = blockIdx.x * 1024 + tid;
  int v = deg[g];
  sh[tid] = v; __syncthreads();
  for (int off = 1; off < 1024; off <<= 1){
    int t = (tid >= off) ? sh[tid - off] : 0;
    __syncthreads();
    sh[tid] += t;
    __syncthreads();
  }
  out[g] = sh[tid] - v;
  if (tid == 1023) part[blockIdx.x] = sh[1023];
}
__global__ void k_scan_part(int* __restrict__ part, int* __restrict__ total_out, int nb){
  int tid = threadIdx.x;                 // 1 wave
  int v = (tid < nb) ? part[tid] : 0;
  int orig = v;
  for (int off = 1; off < 64; off <<= 1){
    int t = __shfl_up(v, off, 64);
    if (tid >= off) v += t;
  }
  if (tid < nb) part[tid] = v - orig;
  if (tid == 63) *total_out = v;
}
__global__ __launch_bounds__(1024) void k_scan_add(int* __restrict__ out, const int* __restrict__ part){
  int g = blockIdx.x * 1024 + threadIdx.x;
  out[g] += part[blockIdx.x];
}
__global__ void k_scatter_graph(const int* __restrict__ head, const int* __restrict__ tail,
                                const int* __restrict__ etype, const int* __restrict__ rowptr,
                                int* __restrict__ cnt, int* __restrict__ pack, int n){
  int e = blockIdx.x * blockDim.x + threadIdx.x;
  if (e >= n) return;
  int h = head[e];
  int pos = rowptr[h] + atomicAdd(&cnt[h], 1);
  pack[pos] = tail[e] | ((etype[e] - 1) << 16);
}
__global__ void k_scatter_int(const int* __restrict__ rows, const int* __restrict__ cols,
                              const float* __restrict__ vals, const int* __restrict__ rowptr,
                              int* __restrict__ cnt, int* __restrict__ ocol,
                              float* __restrict__ oval, int n){
  int e = blockIdx.x * blockDim.x + threadIdx.x;
  if (e >= n) return;
  int r = rows[e];
  int pos = rowptr[r] + atomicAdd(&cnt[r], 1);
  ocol[pos] = cols[e];
  oval[pos] = vals[e];
}

// ---------------- nsq[e][r] = ||ent_e * w_r||^2 ----------------
__global__ __launch_bounds__(256) void k_normsq(const float* __restrict__ ent,
                                                const float* __restrict__ wmat,
                                                float* __restrict__ nsq){
  __shared__ float wl[N_RELM1 * CDIM];
  int tid = threadIdx.x;
  for (int t = tid; t < N_RELM1 * CDIM; t += 256) wl[t] = wmat[t];
  __syncthreads();
  int i = blockIdx.x * 4 + (tid >> 6);
  int lane = tid & 63;
  float v = ent[(size_t)i * CDIM + lane];
  float out = 0.f;
  for (int r = 0; r < N_RELM1; ++r){
    float t = v * wl[r * CDIM + lane];
    float ss = wred_sum(t * t);
    if (lane == r) out = ss;
  }
  if (lane < N_RELM1) nsq[i * N_RELM1 + lane] = out;
}

// ---------------- entity hop ----------------
__global__ __launch_bounds__(256) void k_entity_hop(const float* __restrict__ ent_cur,
                                                    const float* __restrict__ nsq,
                                                    const float* __restrict__ wmat,
                                                    const int* __restrict__ rowptr,
                                                    const int* __restrict__ pack,
                                                    float* __restrict__ ent_next,
                                                    float* __restrict__ res, int hop0){
  __shared__ float wl[N_RELM1 * CDIM];
  int tid = threadIdx.x;
  for (int t = tid; t < N_RELM1 * CDIM; t += 256) wl[t] = wmat[t];
  __syncthreads();
  int i = blockIdx.x * 4 + (tid >> 6);
  int lane = tid & 63;
  int beg = rowptr[i], end = rowptr[i + 1];

  float sm = 0.f;                                   // s >= 0 always
  for (int p = beg + lane; p < end; p += 64){
    int pk = pack[p]; int t = pk & 0xFFFF; int r = pk >> 16;
    sm = fmaxf(sm, nsq[i * N_RELM1 + r] * nsq[t * N_RELM1 + r]);
  }
  sm = wred_max(sm);

  float acc = 0.f, denom = 0.f;
  for (int p = beg; p < end; ++p){
    int pk = pack[p]; int t = pk & 0xFFFF; int r = pk >> 16;
    float s = nsq[i * N_RELM1 + r] * nsq[t * N_RELM1 + r];
    float e = expf(s - sm);
    denom += e;
    acc = fmaf(e * wl[r * CDIM + lane], ent_cur[(size_t)t * CDIM + lane], acc);
  }
  float agg = (end > beg) ? acc / denom : 0.f;
  float nrm = sqrtf(wred_sum(agg * agg));
  float out = agg / fmaxf(nrm, EPSN);
  if (hop0){
    ent_next[(size_t)i * CDIM + lane] = out;
    res[(size_t)i * CDIM + lane] = ent_cur[(size_t)i * CDIM + lane] + out;
  } else {
    res[(size_t)i * CDIM + lane] += out;
  }
}

// ---------------- user hop (hop2 reconstructs u-hat1 = res - base) ----------------
__global__ __launch_bounds__(256) void k_user_hop(const float* __restrict__ base,
                                                  const float* __restrict__ ent_cur,
                                                  const float* __restrict__ wmat,
                                                  const int* __restrict__ rowptr,
                                                  const int* __restrict__ cols,
                                                  const float* __restrict__ vals,
                                                  float* __restrict__ res, int hop0){
  __shared__ float wl[N_RELM1 * CDIM];
  int tid = threadIdx.x;
  for (int t = tid; t < N_RELM1 * CDIM; t += 256) wl[t] = wmat[t];
  __syncthreads();
  int u = blockIdx.x * 4 + (tid >> 6);
  int lane = tid & 63;
  float bv = base[(size_t)u * CDIM + lane];
  float rprev = hop0 ? bv : res[(size_t)u * CDIM + lane];
  float uv = hop0 ? bv : (rprev - bv);

  float dr[N_RELM1];
#pragma unroll
  for (int r = 0; r < N_RELM1; ++r) dr[r] = wred_sum(uv * wl[r * CDIM + lane]);
  float mx = dr[0];
#pragma unroll
  for (int r = 1; r < N_RELM1; ++r) mx = fmaxf(mx, dr[r]);
  float se = 0.f;
#pragma unroll
  for (int r = 0; r < N_RELM1; ++r){ dr[r] = expf(dr[r] - mx); se += dr[r]; }
  float m = 0.f;
#pragma unroll
  for (int r = 0; r < N_RELM1; ++r) m = fmaf(dr[r], wl[r * CDIM + lane], m);
  m /= se;

  int beg = rowptr[u], end = rowptr[u + 1];
  float acc = 0.f;
  for (int p = beg; p < end; ++p)
    acc = fmaf(vals[p], ent_cur[(size_t)cols[p] * CDIM + lane], acc);

  float u2 = acc * (1.f + m);
  float nrm = sqrtf(wred_sum(u2 * u2));
  float out = u2 / fmaxf(nrm, EPSN);
  res[(size_t)u * CDIM + lane] = rprev + out;
}

// ---------------- sparse scatter into dense adjacency ----------------
__global__ void k_scatter_adj(const float* __restrict__ kv, const int* __restrict__ ki,
                              const float* __restrict__ d, float* __restrict__ adj,
                              float coef, int use_atomic){
  int g = blockIdx.x * blockDim.x + threadIdx.x;
  if (g >= N_ENT * TOPK) return;
  int i = g / TOPK;
  int j = ki[g];
  float v = coef * d[i] * kv[g] * d[j];
  if (use_atomic) atomicAdd(&adj[(size_t)i * N_ENT + j], v);
  else            adj[(size_t)i * N_ENT + j] = v;
}

// ---------------- launch ----------------
extern "C" void kernel_launch(void* const* d_in, const int* in_sizes, int n_in,
                              void* d_out, int out_size, void* d_ws, size_t ws_size,
                              hipStream_t stream){
  const float* user_emb   = (const float*)d_in[0];
  const float* entity_emb = (const float*)d_in[1];
  const float* weight     = (const float*)d_in[2];
  const int*   head       = (const int*)d_in[3];
  const int*   tail       = head + E_EDGES;
  const int*   etype      = (const int*)d_in[4];
  const int*   irows      = (const int*)d_in[5];
  const int*   icols      = (const int*)d_in[6];
  const float* ivals      = (const float*)d_in[7];

  float* out_ent = (float*)d_out;
  float* out_usr = out_ent + (size_t)N_ENT * CDIM;
  float* out_adj = out_usr + (size_t)N_USERS * CDIM;

  // ---- workspace layout: padded, non-overlapping ----
  char* W = (char*)d_ws;
  size_t off = 0;
  auto alloc = [&](size_t bytes) -> char* {
    char* p = W + off;
    off = (off + bytes + 1023) & ~(size_t)1023;
    return p;
  };
  float* cn       = (float*)alloc((size_t)N_ENT * CDIM * 4);       // 2 MB
  short* cn_hi    = (short*)alloc((size_t)N_ENT * CDIM * 2);       // 1 MB (permuted)
  short* cn_lo    = (short*)alloc((size_t)N_ENT * CDIM * 2);       // 1 MB (permuted)
  unsigned* skeys = (unsigned*)alloc((size_t)N_ENT * 64 * 8 * 4);  // 16 MB
  float* kv0      = (float*)alloc((size_t)N_ENT * TOPK * 4);
  int*   ki0      = (int*)  alloc((size_t)N_ENT * TOPK * 4);
  float* kv2      = (float*)alloc((size_t)N_ENT * TOPK * 4);
  int*   ki2      = (int*)  alloc((size_t)N_ENT * TOPK * 4);
  float* d0       = (float*)alloc((size_t)N_ENT * 4);
  float* d2       = (float*)alloc((size_t)N_ENT * 4);
  float* nsq      = (float*)alloc((size_t)N_ENT * N_RELM1 * 4);
  float* ent_a    = (float*)alloc((size_t)N_ENT * CDIM * 4);       // 2 MB
  int*   grp_rowptr = (int*)alloc((size_t)(N_ENT + 1) * 4);
  int*   grp_cnt    = (int*)alloc((size_t)N_ENT * 4);
  int*   grp_pack   = (int*)alloc((size_t)E_EDGES * 4);
  int*   int_rowptr = (int*)alloc((size_t)(N_USERS + 1) * 4);
  int*   int_cnt    = (int*)alloc((size_t)N_USERS * 4);
  int*   int_col    = (int*)alloc((size_t)NNZV * 4);
  float* int_val    = (float*)alloc((size_t)NNZV * 4);
  int*   scan_part  = (int*)alloc(256);

  const int EB = (E_EDGES + 255) / 256;

  // ---- graph CSR (by head) ----
  hipMemsetAsync(grp_cnt, 0, N_ENT * 4, stream);
  k_hist<<<EB, 256, 0, stream>>>(head, grp_cnt, E_EDGES);
  k_scan_local<<<N_ENT / 1024, 1024, 0, stream>>>(grp_cnt, grp_rowptr, scan_part);
  k_scan_part<<<1, 64, 0, stream>>>(scan_part, grp_rowptr + N_ENT, N_ENT / 1024);
  k_scan_add<<<N_ENT / 1024, 1024, 0, stream>>>(grp_rowptr, scan_part);
  hipMemsetAsync(grp_cnt, 0, N_ENT * 4, stream);
  k_scatter_graph<<<EB, 256, 0, stream>>>(head, tail, etype, grp_rowptr, grp_cnt, grp_pack, E_EDGES);

  // ---- interaction CSR (by user) ----
  hipMemsetAsync(int_cnt, 0, N_USERS * 4, stream);
  k_hist<<<EB, 256, 0, stream>>>(irows, int_cnt, NNZV);
  k_scan_local<<<N_USERS / 1024, 1024, 0, stream>>>(int_cnt, int_rowptr, scan_part);
  k_scan_part<<<1, 64, 0, stream>>>(scan_part, int_rowptr + N_USERS, N_USERS / 1024);
  k_scan_add<<<N_USERS / 1024, 1024, 0, stream>>>(int_rowptr, scan_part);
  hipMemsetAsync(int_cnt, 0, N_USERS * 4, stream);
  k_scatter_int<<<EB, 256, 0, stream>>>(irows, icols, ivals, int_rowptr, int_cnt, int_col, int_val, NNZV);

  // ---- origin adjacency (sparse form): screen -> refine ----
  k_rownorm_split<<<N_ENT / 4, 256, 0, stream>>>(entity_emb, cn, cn_hi, cn_lo, N_ENT);
  k_sim_topk<<<dim3(N_ENT / 32, 2), 256, 0, stream>>>(cn_hi, cn_lo, skeys);
  k_refine<<<N_ENT / 4, 256, 0, stream>>>(cn, skeys, kv0, ki0, d0);

  // ---- hop 1 ----
  k_normsq<<<N_ENT / 4, 256, 0, stream>>>(entity_emb, weight, nsq);
  k_entity_hop<<<N_ENT / 4, 256, 0, stream>>>(entity_emb, nsq, weight, grp_rowptr, grp_pack, ent_a, out_ent, 1);
  k_user_hop<<<N_USERS / 4, 256, 0, stream>>>(user_emb, entity_emb, weight, int_rowptr, int_col, int_val, out_usr, 1);

  // ---- hop 2 ----
  k_normsq<<<N_ENT / 4, 256, 0, stream>>>(ent_a, weight, nsq);
  k_entity_hop<<<N_ENT / 4, 256, 0, stream>>>(ent_a, nsq, weight, grp_rowptr, grp_pack, ent_a, out_ent, 0);
  k_user_hop<<<N_USERS / 4, 256, 0, stream>>>(user_emb, ent_a, weight, int_rowptr, int_col, int_val, out_usr, 0);

  // ---- final adjacency: screen -> refine ----
  k_rownorm_split<<<N_ENT / 4, 256, 0, stream>>>(out_ent, cn, cn_hi, cn_lo, N_ENT);
  k_sim_topk<<<dim3(N_ENT / 32, 2), 256, 0, stream>>>(cn_hi, cn_lo, skeys);
  k_refine<<<N_ENT / 4, 256, 0, stream>>>(cn, skeys, kv2, ki2, d2);

  hipMemsetAsync(out_adj, 0, (size_t)N_ENT * N_ENT * 4, stream);
  k_scatter_adj<<<(N_ENT * TOPK + 255) / 256, 256, 0, stream>>>(kv0, ki0, d0, out_adj, 0.5f, 0);
  k_scatter_adj<<<(N_ENT * TOPK + 255) / 256, 256, 0, stream>>>(kv2, ki2, d2, out_adj, 0.5f, 1);
}

// Round 7
// 1031.969 us; speedup vs baseline: 1.7645x; 1.0898x over previous
//
#include <hip/hip_runtime.h>
#include <math.h>
#include <float.h>

#define N_USERS 65536
#define N_ENT   8192
#define CDIM    64
#define N_RELM1 15
#define E_EDGES 1000000
#define NNZV    1000000
#define TOPK    10
#define NCAND   12
#define EPSN    1e-12f

typedef float f32x4 __attribute__((ext_vector_type(4)));
typedef short short8 __attribute__((ext_vector_type(8)));

__device__ inline unsigned umaxu(unsigned a, unsigned b){ return a > b ? a : b; }
__device__ inline unsigned uminu(unsigned a, unsigned b){ return a < b ? a : b; }

__device__ inline float wred_sum(float v){
#pragma unroll
  for (int m = 32; m; m >>= 1) v += __shfl_xor(v, m, 64);
  return v;
}
__device__ inline float wred_max(float v){
#pragma unroll
  for (int m = 32; m; m >>= 1) v = fmaxf(v, __shfl_xor(v, m, 64));
  return v;
}

__device__ inline unsigned bf16_rne(float x){
  unsigned u = __float_as_uint(x);
  return (u + 0x7FFFu + ((u >> 16) & 1u)) >> 16;
}

// ---------------- fused: L2-normalize + f32 copy + permuted bf16 hi/lo + optional nsq ----------------
// Permuted layout (MFMA fragment-major): (row,k) -> ((T*2+f)*64 + q*16 + c)*8 + j
// with T=row>>4, c=row&15, f=k>>5, q=(k>>3)&3, j=k&7.
__global__ __launch_bounds__(256) void k_prep(const float* __restrict__ x, float* __restrict__ cn,
                                              short* __restrict__ hi_p, short* __restrict__ lo_p,
                                              const float* __restrict__ wmat, float* __restrict__ nsq,
                                              int do_nsq){
  __shared__ float wl[N_RELM1 * CDIM];
  int tid = threadIdx.x;
  if (do_nsq){
    for (int t = tid; t < N_RELM1 * CDIM; t += 256) wl[t] = wmat[t];
  }
  __syncthreads();
  int w = blockIdx.x * 4 + (tid >> 6);
  int k = tid & 63;
  float v = x[w * CDIM + k];
  float ss = wred_sum(v * v);
  float cv = v / sqrtf(ss);
  cn[w * CDIM + k] = cv;
  unsigned h = bf16_rne(cv);
  float hf = __uint_as_float(h << 16);
  unsigned l2 = bf16_rne(cv - hf);
  int T = w >> 4, c = w & 15;
  int f = k >> 5, q = (k >> 3) & 3, j = k & 7;
  size_t a = ((size_t)(T * 2 + f) * 64 + q * 16 + c) * 8 + j;
  hi_p[a] = (short)h;
  lo_p[a] = (short)l2;
  if (do_nsq){
    float out = 0.f;
    for (int r = 0; r < N_RELM1; ++r){
      float t = v * wl[r * CDIM + k];
      float s2 = wred_sum(t * t);
      if (k == r) out = s2;
    }
    if (k < N_RELM1) nsq[w * N_RELM1 + k] = out;
  }
}

// ---------------- MFMA split-bf16 screening ----------------
__global__ __launch_bounds__(256) void k_sim_topk(const short* __restrict__ hi_p,
                                                  const short* __restrict__ lo_p,
                                                  unsigned* __restrict__ keys){
  const int tid = threadIdx.x;
  const int w = tid >> 6, l = tid & 63;
  const int c = l & 15, q = l >> 4;
  const int rowset = (w >> 1) << 4;
  const int half = w & 1;
  const int cy = blockIdx.y;
  const int row0 = blockIdx.x * 32 + rowset;
  const int R = row0 >> 4;

  const short8* H8 = (const short8*)hi_p;
  const short8* L8 = (const short8*)lo_p;

  const short8 a_hi0 = H8[(size_t)R * 128 + l];
  const short8 a_hi1 = H8[(size_t)R * 128 + 64 + l];
  const short8 a_lo0 = L8[(size_t)R * 128 + l];
  const short8 a_lo1 = L8[(size_t)R * 128 + 64 + l];

  unsigned key[4][8];
#pragma unroll
  for (int s = 0; s < 4; ++s)
#pragma unroll
    for (int t = 0; t < 8; ++t) key[s][t] = 0u;

  const f32x4 z4 = {0.f, 0.f, 0.f, 0.f};
  const int bt = cy * 256 + half * 128;
#pragma unroll 2
  for (int lt = 0; lt < 128; ++lt){
    const size_t bo = (size_t)(bt + lt) * 128 + l;
    short8 b_hi0 = H8[bo];
    short8 b_hi1 = H8[bo + 64];
    short8 b_lo0 = L8[bo];
    short8 b_lo1 = L8[bo + 64];
    f32x4 p0 = __builtin_amdgcn_mfma_f32_16x16x32_bf16(a_hi0, b_hi0, z4, 0, 0, 0);
    f32x4 p1 = __builtin_amdgcn_mfma_f32_16x16x32_bf16(a_hi0, b_lo0, z4, 0, 0, 0);
    f32x4 p2 = __builtin_amdgcn_mfma_f32_16x16x32_bf16(a_lo0, b_hi0, z4, 0, 0, 0);
    p0 = __builtin_amdgcn_mfma_f32_16x16x32_bf16(a_hi1, b_hi1, p0, 0, 0, 0);
    p1 = __builtin_amdgcn_mfma_f32_16x16x32_bf16(a_hi1, b_lo1, p1, 0, 0, 0);
    p2 = __builtin_amdgcn_mfma_f32_16x16x32_bf16(a_lo1, b_hi1, p2, 0, 0, 0);
#pragma unroll
    for (int s = 0; s < 4; ++s){
      float v = p0[s] + p1[s] + p2[s];
      unsigned u = __float_as_uint(v);
      unsigned kk = ((u ^ (unsigned)(((int)u >> 31) | 0x80000000)) & 0xFFFFFF00u) | (unsigned)lt;
#pragma unroll
      for (int i = 7; i >= 1; --i)
        key[s][i] = umaxu(uminu(key[s][i - 1], kk), key[s][i]);
      key[s][0] = umaxu(key[s][0], kk);
    }
  }

#pragma unroll
  for (int s = 0; s < 4; ++s){
    int grow = row0 + 4 * q + s;
    unsigned* kp = keys + ((size_t)grow * 64 + (size_t)(cy * 32 + half * 16 + c)) * 8;
    ((uint4*)kp)[0] = (uint4){key[s][0], key[s][1], key[s][2], key[s][3]};
    ((uint4*)kp)[1] = (uint4){key[s][4], key[s][5], key[s][6], key[s][7]};
  }
}

// ---------------- merge keys -> top-12 -> exact f32 top-10 + D^-1/2 ----------------
__global__ __launch_bounds__(256) void k_refine(const float* __restrict__ cn,
                                                const unsigned* __restrict__ keys,
                                                float* __restrict__ kv, int* __restrict__ ki,
                                                float* __restrict__ dvec){
  int row = blockIdx.x * 4 + (threadIdx.x >> 6);
  int l = threadIdx.x & 63;
  const unsigned* kp = keys + ((size_t)row * 64 + l) * 8;
  uint4 k0 = ((const uint4*)kp)[0], k1 = ((const uint4*)kp)[1];
  unsigned kk0 = k0.x, kk1 = k0.y, kk2 = k0.z, kk3 = k0.w;
  unsigned kk4 = k1.x, kk5 = k1.y, kk6 = k1.z, kk7 = k1.w;
  const int cbase = (l >> 5) * 4096 + ((l >> 4) & 1) * 2048 + (l & 15);

  int ji[NCAND];
#pragma unroll
  for (int t = 0; t < NCAND; ++t){
    unsigned bk = kk0;
    int myc = cbase + (int)(kk0 & 0xFFu) * 16;
    int bc = myc;
#pragma unroll
    for (int m = 32; m; m >>= 1){
      unsigned ok = (unsigned)__shfl_xor((int)bk, m, 64);
      int oc = __shfl_xor(bc, m, 64);
      if (ok > bk || (ok == bk && oc < bc)){ bk = ok; bc = oc; }
    }
    if (kk0 == bk && myc == bc){
      kk0 = kk1; kk1 = kk2; kk2 = kk3; kk3 = kk4; kk4 = kk5; kk5 = kk6; kk6 = kk7; kk7 = 0u;
    }
    ji[t] = bc;
  }

  float v = cn[(size_t)row * CDIM + l];
  float dv[NCAND];
#pragma unroll
  for (int t = 0; t < NCAND; ++t)
    dv[t] = wred_sum(v * cn[(size_t)ji[t] * CDIM + l]);

  unsigned used = 0;
  float rs = 0.f;
  for (int k = 0; k < TOPK; ++k){
    float bv = -FLT_MAX; int bi = 0x7FFFFFFF; int bs = 0;
#pragma unroll
    for (int t = 0; t < NCAND; ++t){
      if (used & (1u << t)) continue;
      if (dv[t] > bv || (dv[t] == bv && ji[t] < bi)){ bv = dv[t]; bi = ji[t]; bs = t; }
    }
    used |= 1u << bs; rs += bv;
    if (l == 0){ kv[(size_t)row * TOPK + k] = bv; ki[(size_t)row * TOPK + k] = bi; }
  }
  if (l == 0) dvec[row] = 1.0f / sqrtf(rs);
}

// ---------------- fused CSR build (both structures) ----------------
__global__ void k_hist2(const int* __restrict__ head, const int* __restrict__ irows,
                        int* __restrict__ cnt_all){
  int e = blockIdx.x * blockDim.x + threadIdx.x;
  if (e < E_EDGES)                  atomicAdd(&cnt_all[head[e]], 1);
  else if (e < E_EDGES + NNZV)      atomicAdd(&cnt_all[N_ENT + irows[e - E_EDGES]], 1);
}

__global__ __launch_bounds__(1024) void k_scan_local2(const int* __restrict__ cnt_all,
                                                      int* __restrict__ rp_grp,
                                                      int* __restrict__ rp_int,
                                                      int* __restrict__ part){
  __shared__ int sh[1024];
  int b = blockIdx.x, tid = threadIdx.x;
  int src = (b < 8) ? (b * 1024 + tid) : (N_ENT + (b - 8) * 1024 + tid);
  int v = cnt_all[src];
  sh[tid] = v; __syncthreads();
  for (int off = 1; off < 1024; off <<= 1){
    int t = (tid >= off) ? sh[tid - off] : 0;
    __syncthreads();
    sh[tid] += t;
    __syncthreads();
  }
  int ex = sh[tid] - v;
  if (b < 8) rp_grp[b * 1024 + tid] = ex;
  else       rp_int[(b - 8) * 1024 + tid] = ex;
  if (tid == 1023) part[b] = sh[1023];
}

__global__ void k_scan_part2(int* __restrict__ part){
  int wid = threadIdx.x >> 6, lane = threadIdx.x & 63;
  if (wid == 0){
    int v = (lane < 8) ? part[lane] : 0;
    int orig = v;
    for (int off = 1; off < 64; off <<= 1){ int t = __shfl_up(v, off, 64); if (lane >= off) v += t; }
    if (lane < 8) part[lane] = v - orig;
  } else {
    int v = part[8 + lane];
    int orig = v;
    for (int off = 1; off < 64; off <<= 1){ int t = __shfl_up(v, off, 64); if (lane >= off) v += t; }
    part[8 + lane] = v - orig;
  }
}

__global__ __launch_bounds__(1024) void k_scan_add2(int* __restrict__ rp_grp, int* __restrict__ rp_int,
                                                    const int* __restrict__ part,
                                                    int* __restrict__ wk_grp, int* __restrict__ wk_int){
  int b = blockIdx.x, tid = threadIdx.x;
  if (b < 8){
    int g = b * 1024 + tid;
    int v = rp_grp[g] + part[b];
    rp_grp[g] = v; wk_grp[g] = v;
  } else {
    int g = (b - 8) * 1024 + tid;
    int v = rp_int[g] + part[b];
    rp_int[g] = v; wk_int[g] = v;
  }
  if (b == 0 && tid == 0){ rp_grp[N_ENT] = E_EDGES; rp_int[N_USERS] = NNZV; }
}

__global__ void k_scatter2(const int* __restrict__ head, const int* __restrict__ tail,
                           const int* __restrict__ etype,
                           const int* __restrict__ irows, const int* __restrict__ icols,
                           const float* __restrict__ ivals,
                           int* __restrict__ wk_grp, int* __restrict__ wk_int,
                           int* __restrict__ pack, int* __restrict__ ocol, float* __restrict__ oval){
  int e = blockIdx.x * blockDim.x + threadIdx.x;
  if (e < E_EDGES){
    int h = head[e];
    int pos = atomicAdd(&wk_grp[h], 1);
    pack[pos] = tail[e] | ((etype[e] - 1) << 16);
  } else if (e < E_EDGES + NNZV){
    int ee = e - E_EDGES;
    int r = irows[ee];
    int pos = atomicAdd(&wk_int[r], 1);
    ocol[pos] = icols[ee];
    oval[pos] = ivals[ee];
  }
}

// ---------------- entity hop: chunked edge-parallel softmax aggregation ----------------
// Phase A per 64-edge chunk: all lanes compute s,e in parallel (one __expf wave-inst per chunk).
// Phase B: serial shfl-broadcast + coalesced row gather + fma (unroll 8).
__global__ __launch_bounds__(256) void k_entity_hop(const float* __restrict__ ent_cur,
                                                    const float* __restrict__ nsq,
                                                    const float* __restrict__ wmat,
                                                    const int* __restrict__ rowptr,
                                                    const int* __restrict__ pack,
                                                    float* __restrict__ ent_next,
                                                    float* __restrict__ nsq_next,
                                                    float* __restrict__ res, int hop0){
  __shared__ float wl[N_RELM1 * CDIM];
  int tid = threadIdx.x;
  for (int t = tid; t < N_RELM1 * CDIM; t += 256) wl[t] = wmat[t];
  __syncthreads();
  int i = blockIdx.x * 4 + (tid >> 6);
  int lane = tid & 63;
  int beg = rowptr[i], end = rowptr[i + 1];

  // segment max (lane-parallel)
  float sm = 0.f;   // s >= 0 always
  for (int p = beg + lane; p < end; p += 64){
    int pk = pack[p]; int t = pk & 0xFFFF; int r = pk >> 16;
    sm = fmaxf(sm, nsq[i * N_RELM1 + r] * nsq[t * N_RELM1 + r]);
  }
  sm = wred_max(sm);

  float acc = 0.f, dsum = 0.f;
  for (int base = beg; base < end; base += 64){
    int p = base + lane;
    int pk = (p < end) ? pack[p] : 0;
    int t = pk & 0xFFFF; int r = pk >> 16;
    float s = nsq[i * N_RELM1 + r] * nsq[t * N_RELM1 + r];
    float e = (p < end) ? __expf(s - sm) : 0.f;
    dsum += e;
    int cnt = end - base; if (cnt > 64) cnt = 64;
#pragma unroll 8
    for (int qq = 0; qq < cnt; ++qq){
      float eq = __shfl(e, qq, 64);
      int tq = __shfl(t, qq, 64);
      int rq = __shfl(r, qq, 64);
      acc = fmaf(eq * wl[rq * CDIM + lane], ent_cur[(size_t)tq * CDIM + lane], acc);
    }
  }
  float denom = wred_sum(dsum);

  float agg = (end > beg) ? acc / denom : 0.f;
  float nrm = sqrtf(wred_sum(agg * agg));
  float out = agg / fmaxf(nrm, EPSN);
  if (hop0){
    ent_next[(size_t)i * CDIM + lane] = out;
    res[(size_t)i * CDIM + lane] = ent_cur[(size_t)i * CDIM + lane] + out;
    // nsq of the hop output for the next hop
    float o = 0.f;
    for (int r = 0; r < N_RELM1; ++r){
      float t = out * wl[r * CDIM + lane];
      float s2 = wred_sum(t * t);
      if (lane == r) o = s2;
    }
    if (lane < N_RELM1) nsq_next[i * N_RELM1 + lane] = o;
  } else {
    res[(size_t)i * CDIM + lane] += out;
  }
}

// ---------------- user hop (hop2 reconstructs u-hat1 = res - base) ----------------
__global__ __launch_bounds__(256) void k_user_hop(const float* __restrict__ base,
                                                  const float* __restrict__ ent_cur,
                                                  const float* __restrict__ wmat,
                                                  const int* __restrict__ rowptr,
                                                  const int* __restrict__ cols,
                                                  const float* __restrict__ vals,
                                                  float* __restrict__ res, int hop0){
  __shared__ float wl[N_RELM1 * CDIM];
  int tid = threadIdx.x;
  for (int t = tid; t < N_RELM1 * CDIM; t += 256) wl[t] = wmat[t];
  __syncthreads();
  int u = blockIdx.x * 4 + (tid >> 6);
  int lane = tid & 63;
  float bv = base[(size_t)u * CDIM + lane];
  float rprev = hop0 ? bv : res[(size_t)u * CDIM + lane];
  float uv = hop0 ? bv : (rprev - bv);

  float dr[N_RELM1];
#pragma unroll
  for (int r = 0; r < N_RELM1; ++r) dr[r] = wred_sum(uv * wl[r * CDIM + lane]);
  float mx = dr[0];
#pragma unroll
  for (int r = 1; r < N_RELM1; ++r) mx = fmaxf(mx, dr[r]);
  float se = 0.f;
#pragma unroll
  for (int r = 0; r < N_RELM1; ++r){ dr[r] = __expf(dr[r] - mx); se += dr[r]; }
  float m = 0.f;
#pragma unroll
  for (int r = 0; r < N_RELM1; ++r) m = fmaf(dr[r], wl[r * CDIM + lane], m);
  m /= se;

  int beg = rowptr[u], end = rowptr[u + 1];
  float acc = 0.f;
#pragma unroll 4
  for (int p = beg; p < end; ++p)
    acc = fmaf(vals[p], ent_cur[(size_t)cols[p] * CDIM + lane], acc);

  float u2 = acc * (1.f + m);
  float nrm = sqrtf(wred_sum(u2 * u2));
  float out = u2 / fmaxf(nrm, EPSN);
  res[(size_t)u * CDIM + lane] = rprev + out;
}

// ---------------- both sparse scatters into dense adjacency (atomic; <=2 addends/cell) ----------------
__global__ void k_scatter_adj2(const float* __restrict__ kv0, const int* __restrict__ ki0,
                               const float* __restrict__ d0,
                               const float* __restrict__ kv2, const int* __restrict__ ki2,
                               const float* __restrict__ d2,
                               float* __restrict__ adj){
  int g = blockIdx.x * blockDim.x + threadIdx.x;
  const int n = N_ENT * TOPK;
  if (g < n){
    int i = g / TOPK; int j = ki0[g];
    atomicAdd(&adj[(size_t)i * N_ENT + j], 0.5f * d0[i] * kv0[g] * d0[j]);
  } else if (g < 2 * n){
    int gg = g - n;
    int i = gg / TOPK; int j = ki2[gg];
    atomicAdd(&adj[(size_t)i * N_ENT + j], 0.5f * d2[i] * kv2[gg] * d2[j]);
  }
}

// ---------------- launch ----------------
extern "C" void kernel_launch(void* const* d_in, const int* in_sizes, int n_in,
                              void* d_out, int out_size, void* d_ws, size_t ws_size,
                              hipStream_t stream){
  const float* user_emb   = (const float*)d_in[0];
  const float* entity_emb = (const float*)d_in[1];
  const float* weight     = (const float*)d_in[2];
  const int*   head       = (const int*)d_in[3];
  const int*   tail       = head + E_EDGES;
  const int*   etype      = (const int*)d_in[4];
  const int*   irows      = (const int*)d_in[5];
  const int*   icols      = (const int*)d_in[6];
  const float* ivals      = (const float*)d_in[7];

  float* out_ent = (float*)d_out;
  float* out_usr = out_ent + (size_t)N_ENT * CDIM;
  float* out_adj = out_usr + (size_t)N_USERS * CDIM;

  // ---- workspace (padded, non-overlapping) ----
  char* W = (char*)d_ws;
  size_t off = 0;
  auto alloc = [&](size_t bytes) -> char* {
    char* p = W + off;
    off = (off + bytes + 1023) & ~(size_t)1023;
    return p;
  };
  float* cn       = (float*)alloc((size_t)N_ENT * CDIM * 4);
  short* cn_hi    = (short*)alloc((size_t)N_ENT * CDIM * 2);
  short* cn_lo    = (short*)alloc((size_t)N_ENT * CDIM * 2);
  unsigned* skeys = (unsigned*)alloc((size_t)N_ENT * 64 * 8 * 4);  // 16 MB
  float* kv0      = (float*)alloc((size_t)N_ENT * TOPK * 4);
  int*   ki0      = (int*)  alloc((size_t)N_ENT * TOPK * 4);
  float* kv2      = (float*)alloc((size_t)N_ENT * TOPK * 4);
  int*   ki2      = (int*)  alloc((size_t)N_ENT * TOPK * 4);
  float* d0       = (float*)alloc((size_t)N_ENT * 4);
  float* d2       = (float*)alloc((size_t)N_ENT * 4);
  float* nsq_a    = (float*)alloc((size_t)N_ENT * N_RELM1 * 4);
  float* nsq_b    = (float*)alloc((size_t)N_ENT * N_RELM1 * 4);
  float* ent_a    = (float*)alloc((size_t)N_ENT * CDIM * 4);
  int*   cnt_all  = (int*)  alloc((size_t)(N_ENT + N_USERS) * 4);
  int*   rp_grp   = (int*)  alloc((size_t)(N_ENT + 1) * 4);
  int*   wk_grp   = (int*)  alloc((size_t)N_ENT * 4);
  int*   grp_pack = (int*)  alloc((size_t)E_EDGES * 4);
  int*   rp_int   = (int*)  alloc((size_t)(N_USERS + 1) * 4);
  int*   wk_int   = (int*)  alloc((size_t)N_USERS * 4);
  int*   int_col  = (int*)  alloc((size_t)NNZV * 4);
  float* int_val  = (float*)alloc((size_t)NNZV * 4);
  int*   part     = (int*)  alloc(128 * 4);

  const int TOT = E_EDGES + NNZV;
  const int TB  = (TOT + 255) / 256;

  // ---- fused CSR build (graph-by-head + interaction-by-user) ----
  hipMemsetAsync(cnt_all, 0, (size_t)(N_ENT + N_USERS) * 4, stream);
  k_hist2<<<TB, 256, 0, stream>>>(head, irows, cnt_all);
  k_scan_local2<<<72, 1024, 0, stream>>>(cnt_all, rp_grp, rp_int, part);
  k_scan_part2<<<1, 128, 0, stream>>>(part);
  k_scan_add2<<<72, 1024, 0, stream>>>(rp_grp, rp_int, part, wk_grp, wk_int);
  k_scatter2<<<TB, 256, 0, stream>>>(head, tail, etype, irows, icols, ivals,
                                     wk_grp, wk_int, grp_pack, int_col, int_val);

  // ---- origin adjacency screen+refine (also produces nsq of entity_emb for hop 1) ----
  k_prep<<<N_ENT / 4, 256, 0, stream>>>(entity_emb, cn, cn_hi, cn_lo, weight, nsq_a, 1);
  k_sim_topk<<<dim3(N_ENT / 32, 2), 256, 0, stream>>>(cn_hi, cn_lo, skeys);
  k_refine<<<N_ENT / 4, 256, 0, stream>>>(cn, skeys, kv0, ki0, d0);

  // ---- hop 1 (entity hop also emits nsq of its output for hop 2) ----
  k_entity_hop<<<N_ENT / 4, 256, 0, stream>>>(entity_emb, nsq_a, weight, rp_grp, grp_pack,
                                              ent_a, nsq_b, out_ent, 1);
  k_user_hop<<<N_USERS / 4, 256, 0, stream>>>(user_emb, entity_emb, weight, rp_int,
                                              int_col, int_val, out_usr, 1);

  // ---- hop 2 ----
  k_entity_hop<<<N_ENT / 4, 256, 0, stream>>>(ent_a, nsq_b, weight, rp_grp, grp_pack,
                                              ent_a, nsq_b, out_ent, 0);
  k_user_hop<<<N_USERS / 4, 256, 0, stream>>>(user_emb, ent_a, weight, rp_int,
                                              int_col, int_val, out_usr, 0);

  // ---- final adjacency screen+refine ----
  k_prep<<<N_ENT / 4, 256, 0, stream>>>(out_ent, cn, cn_hi, cn_lo, weight, nsq_a, 0);
  k_sim_topk<<<dim3(N_ENT / 32, 2), 256, 0, stream>>>(cn_hi, cn_lo, skeys);
  k_refine<<<N_ENT / 4, 256, 0, stream>>>(cn, skeys, kv2, ki2, d2);

  // ---- dense output ----
  hipMemsetAsync(out_adj, 0, (size_t)N_ENT * N_ENT * 4, stream);
  k_scatter_adj2<<<(2 * N_ENT * TOPK + 255) / 256, 256, 0, stream>>>(kv0, ki0, d0, kv2, ki2, d2, out_adj);
}

// Round 8
// 1026.353 us; speedup vs baseline: 1.7742x; 1.0055x over previous
//
#include <hip/hip_runtime.h>
#include <math.h>
#include <float.h>

#define N_USERS 65536
#define N_ENT   8192
#define CDIM    64
#define N_RELM1 15
#define E_EDGES 1000000
#define NNZV    1000000
#define TOPK    10
#define NCAND   16
#define KTOT    (N_ENT + N_USERS)
#define EPSN    1e-12f

typedef float f32x4 __attribute__((ext_vector_type(4)));
typedef short short8 __attribute__((ext_vector_type(8)));

__device__ inline unsigned umaxu(unsigned a, unsigned b){ return a > b ? a : b; }
__device__ inline unsigned uminu(unsigned a, unsigned b){ return a < b ? a : b; }

__device__ inline float wred_sum(float v){
#pragma unroll
  for (int m = 32; m; m >>= 1) v += __shfl_xor(v, m, 64);
  return v;
}
__device__ inline float wred_max(float v){
#pragma unroll
  for (int m = 32; m; m >>= 1) v = fmaxf(v, __shfl_xor(v, m, 64));
  return v;
}

__device__ inline unsigned bf16_rne(float x){
  unsigned u = __float_as_uint(x);
  return (u + 0x7FFFu + ((u >> 16) & 1u)) >> 16;
}

// ---------------- fused: L2-normalize + f32 copy + permuted bf16 hi + optional nsq ----------------
// Permuted layout (MFMA fragment-major): (row,k) -> ((T*2+f)*64 + q*16 + c)*8 + j
__global__ __launch_bounds__(256) void k_prep(const float* __restrict__ x, float* __restrict__ cn,
                                              short* __restrict__ hi_p,
                                              const float* __restrict__ wmat, float* __restrict__ nsq,
                                              int do_nsq){
  __shared__ float wl[N_RELM1 * CDIM];
  int tid = threadIdx.x;
  if (do_nsq){
    for (int t = tid; t < N_RELM1 * CDIM; t += 256) wl[t] = wmat[t];
  }
  __syncthreads();
  int w = blockIdx.x * 4 + (tid >> 6);
  int k = tid & 63;
  float v = x[w * CDIM + k];
  float ss = wred_sum(v * v);
  float cv = v / sqrtf(ss);
  cn[w * CDIM + k] = cv;
  unsigned h = bf16_rne(cv);
  int T = w >> 4, c = w & 15;
  int f = k >> 5, q = (k >> 3) & 3, j = k & 7;
  size_t a = ((size_t)(T * 2 + f) * 64 + q * 16 + c) * 8 + j;
  hi_p[a] = (short)h;
  if (do_nsq){
    float out = 0.f;
    for (int r = 0; r < N_RELM1; ++r){
      float t = v * wl[r * CDIM + k];
      float s2 = wred_sum(t * t);
      if (k == r) out = s2;
    }
    if (k < N_RELM1) nsq[w * N_RELM1 + k] = out;
  }
}

// ---------------- MFMA hi-only screening (exact refine recovers precision) ----------------
// grid (N_ENT/32, 2); wave w: rows (w>>1)*16, col range [cy*4096+(w&1)*2048, +2048) as 128 tiles.
// Per lane: branch-free sorted top-8 packed keys per s (4 rows/lane).
__global__ __launch_bounds__(256) void k_sim_topk(const short* __restrict__ hi_p,
                                                  unsigned* __restrict__ keys){
  const int tid = threadIdx.x;
  const int w = tid >> 6, l = tid & 63;
  const int c = l & 15, q = l >> 4;
  const int rowset = (w >> 1) << 4;
  const int half = w & 1;
  const int cy = blockIdx.y;
  const int row0 = blockIdx.x * 32 + rowset;
  const int R = row0 >> 4;

  const short8* H8 = (const short8*)hi_p;

  const short8 a_hi0 = H8[(size_t)R * 128 + l];
  const short8 a_hi1 = H8[(size_t)R * 128 + 64 + l];

  unsigned key[4][8];
#pragma unroll
  for (int s = 0; s < 4; ++s)
#pragma unroll
    for (int t = 0; t < 8; ++t) key[s][t] = 0u;

  const f32x4 z4 = {0.f, 0.f, 0.f, 0.f};
  const int bt = cy * 256 + half * 128;
#pragma unroll 2
  for (int lt = 0; lt < 128; ++lt){
    const size_t bo = (size_t)(bt + lt) * 128 + l;
    short8 b_hi0 = H8[bo];
    short8 b_hi1 = H8[bo + 64];
    f32x4 p0 = __builtin_amdgcn_mfma_f32_16x16x32_bf16(a_hi0, b_hi0, z4, 0, 0, 0);
    p0 = __builtin_amdgcn_mfma_f32_16x16x32_bf16(a_hi1, b_hi1, p0, 0, 0, 0);
#pragma unroll
    for (int s = 0; s < 4; ++s){
      float v = p0[s];
      unsigned u = __float_as_uint(v);
      unsigned kk = ((u ^ (unsigned)(((int)u >> 31) | 0x80000000)) & 0xFFFFFF00u) | (unsigned)lt;
#pragma unroll
      for (int i = 7; i >= 1; --i)
        key[s][i] = umaxu(uminu(key[s][i - 1], kk), key[s][i]);
      key[s][0] = umaxu(key[s][0], kk);
    }
  }

#pragma unroll
  for (int s = 0; s < 4; ++s){
    int grow = row0 + 4 * q + s;
    unsigned* kp = keys + ((size_t)grow * 64 + (size_t)(cy * 32 + half * 16 + c)) * 8;
    ((uint4*)kp)[0] = (uint4){key[s][0], key[s][1], key[s][2], key[s][3]};
    ((uint4*)kp)[1] = (uint4){key[s][4], key[s][5], key[s][6], key[s][7]};
  }
}

// ---------------- merge 64x8 keys -> top-16 -> exact f32 top-10 + D^-1/2 ----------------
__global__ __launch_bounds__(256) void k_refine(const float* __restrict__ cn,
                                                const unsigned* __restrict__ keys,
                                                float* __restrict__ kv, int* __restrict__ ki,
                                                float* __restrict__ dvec){
  int row = blockIdx.x * 4 + (threadIdx.x >> 6);
  int l = threadIdx.x & 63;
  const unsigned* kp = keys + ((size_t)row * 64 + l) * 8;
  uint4 k0 = ((const uint4*)kp)[0], k1 = ((const uint4*)kp)[1];
  unsigned kk0 = k0.x, kk1 = k0.y, kk2 = k0.z, kk3 = k0.w;
  unsigned kk4 = k1.x, kk5 = k1.y, kk6 = k1.z, kk7 = k1.w;
  const int cbase = (l >> 5) * 4096 + ((l >> 4) & 1) * 2048 + (l & 15);

  int ji[NCAND];
#pragma unroll
  for (int t = 0; t < NCAND; ++t){
    unsigned bk = kk0;
    int myc = cbase + (int)(kk0 & 0xFFu) * 16;
    int bc = myc;
#pragma unroll
    for (int m = 32; m; m >>= 1){
      unsigned ok = (unsigned)__shfl_xor((int)bk, m, 64);
      int oc = __shfl_xor(bc, m, 64);
      if (ok > bk || (ok == bk && oc < bc)){ bk = ok; bc = oc; }
    }
    if (kk0 == bk && myc == bc){   // pop my head (sentinel 0 < any real key)
      kk0 = kk1; kk1 = kk2; kk2 = kk3; kk3 = kk4; kk4 = kk5; kk5 = kk6; kk6 = kk7; kk7 = 0u;
    }
    ji[t] = bc;
  }

  float v = cn[(size_t)row * CDIM + l];
  float dv[NCAND];
#pragma unroll
  for (int t = 0; t < NCAND; ++t)
    dv[t] = wred_sum(v * cn[(size_t)ji[t] * CDIM + l]);

  unsigned used = 0;
  float rs = 0.f;
  for (int k = 0; k < TOPK; ++k){
    float bv = -FLT_MAX; int bi = 0x7FFFFFFF; int bs = 0;
#pragma unroll
    for (int t = 0; t < NCAND; ++t){
      if (used & (1u << t)) continue;
      if (dv[t] > bv || (dv[t] == bv && ji[t] < bi)){ bv = dv[t]; bi = ji[t]; bs = t; }
    }
    used |= 1u << bs; rs += bv;
    if (l == 0){ kv[(size_t)row * TOPK + k] = bv; ki[(size_t)row * TOPK + k] = bi; }
  }
  if (l == 0) dvec[row] = 1.0f / sqrtf(rs);
}

// ---------------- striped fused CSR build (8 stripes cut atomic contention / XCD bouncing) ----------------
__global__ void k_hist8(const int* __restrict__ head, const int* __restrict__ irows,
                        int* __restrict__ cnt8){
  int e = blockIdx.x * blockDim.x + threadIdx.x;
  int s = blockIdx.x & 7;
  if (e < E_EDGES)             atomicAdd(&cnt8[s * KTOT + head[e]], 1);
  else if (e < E_EDGES + NNZV) atomicAdd(&cnt8[s * KTOT + N_ENT + irows[e - E_EDGES]], 1);
}

__global__ __launch_bounds__(1024) void k_scan_local8(const int* __restrict__ cnt8,
                                                      int* __restrict__ rp_grp,
                                                      int* __restrict__ rp_int,
                                                      int* __restrict__ cur8,
                                                      int* __restrict__ part){
  __shared__ int sh[1024];
  int b = blockIdx.x, tid = threadIdx.x;
  int keyidx = b * 1024 + tid;
  int c[8]; int tot = 0;
#pragma unroll
  for (int s = 0; s < 8; ++s){ c[s] = cnt8[s * KTOT + keyidx]; tot += c[s]; }
  sh[tid] = tot; __syncthreads();
  for (int off = 1; off < 1024; off <<= 1){
    int t = (tid >= off) ? sh[tid - off] : 0;
    __syncthreads();
    sh[tid] += t;
    __syncthreads();
  }
  int ex = sh[tid] - tot;
  if (keyidx < N_ENT) rp_grp[keyidx] = ex;
  else                rp_int[keyidx - N_ENT] = ex;
  int run = ex;
#pragma unroll
  for (int s = 0; s < 8; ++s){ cur8[s * KTOT + keyidx] = run; run += c[s]; }
  if (tid == 1023) part[b] = sh[1023];
}

__global__ void k_scan_part8(int* __restrict__ part){
  int wid = threadIdx.x >> 6, lane = threadIdx.x & 63;
  if (wid == 0){
    int v = (lane < 8) ? part[lane] : 0;
    int orig = v;
    for (int off = 1; off < 64; off <<= 1){ int t = __shfl_up(v, off, 64); if (lane >= off) v += t; }
    if (lane < 8) part[lane] = v - orig;
  } else {
    int v = part[8 + lane];
    int orig = v;
    for (int off = 1; off < 64; off <<= 1){ int t = __shfl_up(v, off, 64); if (lane >= off) v += t; }
    part[8 + lane] = v - orig;
  }
}

__global__ __launch_bounds__(1024) void k_scan_add8(int* __restrict__ rp_grp, int* __restrict__ rp_int,
                                                    int* __restrict__ cur8,
                                                    const int* __restrict__ part){
  int b = blockIdx.x, tid = threadIdx.x;
  int keyidx = b * 1024 + tid;
  int p = part[b];
  if (keyidx < N_ENT) rp_grp[keyidx] += p;
  else                rp_int[keyidx - N_ENT] += p;
#pragma unroll
  for (int s = 0; s < 8; ++s) cur8[s * KTOT + keyidx] += p;
  if (b == 0 && tid == 0){ rp_grp[N_ENT] = E_EDGES; rp_int[N_USERS] = NNZV; }
}

__global__ void k_scatter8(const int* __restrict__ head, const int* __restrict__ tail,
                           const int* __restrict__ etype,
                           const int* __restrict__ irows, const int* __restrict__ icols,
                           const float* __restrict__ ivals,
                           int* __restrict__ cur8,
                           int* __restrict__ pack, int* __restrict__ ocol, float* __restrict__ oval){
  int e = blockIdx.x * blockDim.x + threadIdx.x;
  int s = blockIdx.x & 7;
  if (e < E_EDGES){
    int h = head[e];
    int pos = atomicAdd(&cur8[s * KTOT + h], 1);
    pack[pos] = tail[e] | ((etype[e] - 1) << 16);
  } else if (e < E_EDGES + NNZV){
    int ee = e - E_EDGES;
    int r = irows[ee];
    int pos = atomicAdd(&cur8[s * KTOT + N_ENT + r], 1);
    ocol[pos] = icols[ee];
    oval[pos] = ivals[ee];
  }
}

// ---------------- entity hop: chunked edge-parallel softmax aggregation ----------------
__global__ __launch_bounds__(256) void k_entity_hop(const float* __restrict__ ent_cur,
                                                    const float* __restrict__ nsq,
                                                    const float* __restrict__ wmat,
                                                    const int* __restrict__ rowptr,
                                                    const int* __restrict__ pack,
                                                    float* __restrict__ ent_next,
                                                    float* __restrict__ nsq_next,
                                                    float* __restrict__ res, int hop0){
  __shared__ float wl[N_RELM1 * CDIM];
  int tid = threadIdx.x;
  for (int t = tid; t < N_RELM1 * CDIM; t += 256) wl[t] = wmat[t];
  __syncthreads();
  int i = blockIdx.x * 4 + (tid >> 6);
  int lane = tid & 63;
  int beg = rowptr[i], end = rowptr[i + 1];

  float sm = 0.f;   // s >= 0 always
  for (int p = beg + lane; p < end; p += 64){
    int pk = pack[p]; int t = pk & 0xFFFF; int r = pk >> 16;
    sm = fmaxf(sm, nsq[i * N_RELM1 + r] * nsq[t * N_RELM1 + r]);
  }
  sm = wred_max(sm);

  float acc = 0.f, dsum = 0.f;
  for (int base = beg; base < end; base += 64){
    int p = base + lane;
    int pk = (p < end) ? pack[p] : 0;
    int t = pk & 0xFFFF; int r = pk >> 16;
    float s = nsq[i * N_RELM1 + r] * nsq[t * N_RELM1 + r];
    float e = (p < end) ? __expf(s - sm) : 0.f;
    dsum += e;
    int cnt = end - base; if (cnt > 64) cnt = 64;
#pragma unroll 8
    for (int qq = 0; qq < cnt; ++qq){
      float eq = __shfl(e, qq, 64);
      int tq = __shfl(t, qq, 64);
      int rq = __shfl(r, qq, 64);
      acc = fmaf(eq * wl[rq * CDIM + lane], ent_cur[(size_t)tq * CDIM + lane], acc);
    }
  }
  float denom = wred_sum(dsum);

  float agg = (end > beg) ? acc / denom : 0.f;
  float nrm = sqrtf(wred_sum(agg * agg));
  float out = agg / fmaxf(nrm, EPSN);
  if (hop0){
    ent_next[(size_t)i * CDIM + lane] = out;
    res[(size_t)i * CDIM + lane] = ent_cur[(size_t)i * CDIM + lane] + out;
    float o = 0.f;
    for (int r = 0; r < N_RELM1; ++r){
      float t = out * wl[r * CDIM + lane];
      float s2 = wred_sum(t * t);
      if (lane == r) o = s2;
    }
    if (lane < N_RELM1) nsq_next[i * N_RELM1 + lane] = o;
  } else {
    res[(size_t)i * CDIM + lane] += out;
  }
}

// ---------------- user hop (hop2 reconstructs u-hat1 = res - base) ----------------
__global__ __launch_bounds__(256) void k_user_hop(const float* __restrict__ base,
                                                  const float* __restrict__ ent_cur,
                                                  const float* __restrict__ wmat,
                                                  const int* __restrict__ rowptr,
                                                  const int* __restrict__ cols,
                                                  const float* __restrict__ vals,
                                                  float* __restrict__ res, int hop0){
  __shared__ float wl[N_RELM1 * CDIM];
  int tid = threadIdx.x;
  for (int t = tid; t < N_RELM1 * CDIM; t += 256) wl[t] = wmat[t];
  __syncthreads();
  int u = blockIdx.x * 4 + (tid >> 6);
  int lane = tid & 63;
  float bv = base[(size_t)u * CDIM + lane];
  float rprev = hop0 ? bv : res[(size_t)u * CDIM + lane];
  float uv = hop0 ? bv : (rprev - bv);

  float dr[N_RELM1];
#pragma unroll
  for (int r = 0; r < N_RELM1; ++r) dr[r] = wred_sum(uv * wl[r * CDIM + lane]);
  float mx = dr[0];
#pragma unroll
  for (int r = 1; r < N_RELM1; ++r) mx = fmaxf(mx, dr[r]);
  float se = 0.f;
#pragma unroll
  for (int r = 0; r < N_RELM1; ++r){ dr[r] = __expf(dr[r] - mx); se += dr[r]; }
  float m = 0.f;
#pragma unroll
  for (int r = 0; r < N_RELM1; ++r) m = fmaf(dr[r], wl[r * CDIM + lane], m);
  m /= se;

  int beg = rowptr[u], end = rowptr[u + 1];
  float acc = 0.f;
#pragma unroll 4
  for (int p = beg; p < end; ++p)
    acc = fmaf(vals[p], ent_cur[(size_t)cols[p] * CDIM + lane], acc);

  float u2 = acc * (1.f + m);
  float nrm = sqrtf(wred_sum(u2 * u2));
  float out = u2 / fmaxf(nrm, EPSN);
  res[(size_t)u * CDIM + lane] = rprev + out;
}

// ---------------- fused zero + both sparse scatters: one row per block ----------------
__global__ __launch_bounds__(256) void k_adj_write(const float* __restrict__ kv0, const int* __restrict__ ki0,
                                                   const float* __restrict__ d0,
                                                   const float* __restrict__ kv2, const int* __restrict__ ki2,
                                                   const float* __restrict__ d2,
                                                   float* __restrict__ adj){
  int i = blockIdx.x;
  int tid = threadIdx.x;
  float4* rowp = (float4*)(adj + (size_t)i * N_ENT);
  const float4 z = {0.f, 0.f, 0.f, 0.f};
#pragma unroll
  for (int k = 0; k < 8; ++k) rowp[k * 256 + tid] = z;
  __syncthreads();
  if (tid < TOPK){
    int j = ki0[i * TOPK + tid];
    atomicAdd(&adj[(size_t)i * N_ENT + j], 0.5f * d0[i] * kv0[i * TOPK + tid] * d0[j]);
  } else if (tid < 2 * TOPK){
    int t = tid - TOPK;
    int j = ki2[i * TOPK + t];
    atomicAdd(&adj[(size_t)i * N_ENT + j], 0.5f * d2[i] * kv2[i * TOPK + t] * d2[j]);
  }
}

// ---------------- launch ----------------
extern "C" void kernel_launch(void* const* d_in, const int* in_sizes, int n_in,
                              void* d_out, int out_size, void* d_ws, size_t ws_size,
                              hipStream_t stream){
  const float* user_emb   = (const float*)d_in[0];
  const float* entity_emb = (const float*)d_in[1];
  const float* weight     = (const float*)d_in[2];
  const int*   head       = (const int*)d_in[3];
  const int*   tail       = head + E_EDGES;
  const int*   etype      = (const int*)d_in[4];
  const int*   irows      = (const int*)d_in[5];
  const int*   icols      = (const int*)d_in[6];
  const float* ivals      = (const float*)d_in[7];

  float* out_ent = (float*)d_out;
  float* out_usr = out_ent + (size_t)N_ENT * CDIM;
  float* out_adj = out_usr + (size_t)N_USERS * CDIM;

  // ---- workspace (padded, non-overlapping) ----
  char* W = (char*)d_ws;
  size_t off = 0;
  auto alloc = [&](size_t bytes) -> char* {
    char* p = W + off;
    off = (off + bytes + 1023) & ~(size_t)1023;
    return p;
  };
  float* cn       = (float*)alloc((size_t)N_ENT * CDIM * 4);
  short* cn_hi    = (short*)alloc((size_t)N_ENT * CDIM * 2);
  unsigned* skeys = (unsigned*)alloc((size_t)N_ENT * 64 * 8 * 4);  // 16 MB
  float* kv0      = (float*)alloc((size_t)N_ENT * TOPK * 4);
  int*   ki0      = (int*)  alloc((size_t)N_ENT * TOPK * 4);
  float* kv2      = (float*)alloc((size_t)N_ENT * TOPK * 4);
  int*   ki2      = (int*)  alloc((size_t)N_ENT * TOPK * 4);
  float* d0       = (float*)alloc((size_t)N_ENT * 4);
  float* d2       = (float*)alloc((size_t)N_ENT * 4);
  float* nsq_a    = (float*)alloc((size_t)N_ENT * N_RELM1 * 4);
  float* nsq_b    = (float*)alloc((size_t)N_ENT * N_RELM1 * 4);
  float* ent_a    = (float*)alloc((size_t)N_ENT * CDIM * 4);
  int*   cnt8     = (int*)  alloc((size_t)8 * KTOT * 4);           // 2.36 MB
  int*   cur8     = (int*)  alloc((size_t)8 * KTOT * 4);           // 2.36 MB
  int*   rp_grp   = (int*)  alloc((size_t)(N_ENT + 1) * 4);
  int*   grp_pack = (int*)  alloc((size_t)E_EDGES * 4);
  int*   rp_int   = (int*)  alloc((size_t)(N_USERS + 1) * 4);
  int*   int_col  = (int*)  alloc((size_t)NNZV * 4);
  float* int_val  = (float*)alloc((size_t)NNZV * 4);
  int*   part     = (int*)  alloc(128 * 4);

  const int TOT = E_EDGES + NNZV;
  const int TB  = (TOT + 255) / 256;

  // ---- striped fused CSR build ----
  hipMemsetAsync(cnt8, 0, (size_t)8 * KTOT * 4, stream);
  k_hist8<<<TB, 256, 0, stream>>>(head, irows, cnt8);
  k_scan_local8<<<KTOT / 1024, 1024, 0, stream>>>(cnt8, rp_grp, rp_int, cur8, part);
  k_scan_part8<<<1, 128, 0, stream>>>(part);
  k_scan_add8<<<KTOT / 1024, 1024, 0, stream>>>(rp_grp, rp_int, cur8, part);
  k_scatter8<<<TB, 256, 0, stream>>>(head, tail, etype, irows, icols, ivals,
                                     cur8, grp_pack, int_col, int_val);

  // ---- origin adjacency screen+refine (+ nsq of entity_emb for hop 1) ----
  k_prep<<<N_ENT / 4, 256, 0, stream>>>(entity_emb, cn, cn_hi, weight, nsq_a, 1);
  k_sim_topk<<<dim3(N_ENT / 32, 2), 256, 0, stream>>>(cn_hi, skeys);
  k_refine<<<N_ENT / 4, 256, 0, stream>>>(cn, skeys, kv0, ki0, d0);

  // ---- hop 1 (entity hop also emits nsq of its output for hop 2) ----
  k_entity_hop<<<N_ENT / 4, 256, 0, stream>>>(entity_emb, nsq_a, weight, rp_grp, grp_pack,
                                              ent_a, nsq_b, out_ent, 1);
  k_user_hop<<<N_USERS / 4, 256, 0, stream>>>(user_emb, entity_emb, weight, rp_int,
                                              int_col, int_val, out_usr, 1);

  // ---- hop 2 ----
  k_entity_hop<<<N_ENT / 4, 256, 0, stream>>>(ent_a, nsq_b, weight, rp_grp, grp_pack,
                                              ent_a, nsq_b, out_ent, 0);
  k_user_hop<<<N_USERS / 4, 256, 0, stream>>>(user_emb, ent_a, weight, rp_int,
                                              int_col, int_val, out_usr, 0);

  // ---- final adjacency screen+refine ----
  k_prep<<<N_ENT / 4, 256, 0, stream>>>(out_ent, cn, cn_hi, weight, nsq_a, 0);
  k_sim_topk<<<dim3(N_ENT / 32, 2), 256, 0, stream>>>(cn_hi, skeys);
  k_refine<<<N_ENT / 4, 256, 0, stream>>>(cn, skeys, kv2, ki2, d2);

  // ---- dense output: fused zero + scatter ----
  k_adj_write<<<N_ENT, 256, 0, stream>>>(kv0, ki0, d0, kv2, ki2, d2, out_adj);
}